// Round 7
// baseline (120.558 us; speedup 1.0000x reference)
//
#include <hip/hip_runtime.h>

typedef __bf16 bf16;
typedef __bf16 bf16x4 __attribute__((ext_vector_type(4)));
typedef __bf16 bf16x8 __attribute__((ext_vector_type(8)));
typedef float f32x4 __attribute__((ext_vector_type(4)));

#define MFMA16(a, b, c) __builtin_amdgcn_mfma_f32_16x16x32_bf16((a), (b), (c), 0, 0, 0)

// global -> LDS DMA, 16B per lane; LDS dest is wave-uniform base + lane*16.
#define GLD16(gp, lp)                                                              \
  __builtin_amdgcn_global_load_lds(                                                \
      (const __attribute__((address_space(1))) unsigned int*)(unsigned long long)(gp), \
      (__attribute__((address_space(3))) unsigned int*)(unsigned long long)(lp), 16, 0, 0)

#define LGKM0_BARRIER()                                   \
  do {                                                    \
    asm volatile("s_waitcnt lgkmcnt(0)" ::: "memory");    \
    __builtin_amdgcn_sched_barrier(0);                    \
    __builtin_amdgcn_s_barrier();                         \
    __builtin_amdgcn_sched_barrier(0);                    \
  } while (0)

// B=256, T=320, C=1024, H=64;  M = B*T = 81920
// ws (bf16): Wt [3][64][1024] | Qw [81920][64] | Kw [81920][64] | Vt [256][64][320]

// ---------------- Kernel 0: W -> Wt (bf16, [mat][h][k]) ----------------
__global__ __launch_bounds__(256) void wtrans_kernel(
    const float* __restrict__ Wk, const float* __restrict__ Wq,
    const float* __restrict__ Wv, bf16* __restrict__ Wt) {
  __shared__ bf16 tile[64][65];
  const int mat = blockIdx.x >> 4;
  const int kt = (blockIdx.x & 15) << 6;
  const float* __restrict__ W = (mat == 0) ? Wk : ((mat == 1) ? Wq : Wv);
  const int tid = threadIdx.x;
#pragma unroll
  for (int j = 0; j < 16; ++j) {
    const int i = tid + 256 * j;
    const int k = i >> 6, h = i & 63;
    tile[h][k] = (bf16)W[(kt + k) * 64 + h];
  }
  __syncthreads();
#pragma unroll
  for (int j = 0; j < 16; ++j) {
    const int i = tid + 256 * j;
    const int h = i >> 6, k = i & 63;
    Wt[mat * 65536 + h * 1024 + kt + k] = tile[h][k];
  }
}

// ---------------- Kernel 1: fused QKV projection (frozen, round-5 version) ----------------
__global__ __launch_bounds__(256) void qkv_kernel(
    const float* __restrict__ x, const bf16* __restrict__ Wt,
    bf16* __restrict__ Qw, bf16* __restrict__ Kw, bf16* __restrict__ Vt) {
  __shared__ float xs3[3][64][64];  // 48 KB
  const int tid = threadIdx.x;
  const int w = tid >> 6, l = tid & 63;
  const int lr = l & 15, lg = l >> 4;
  const int m0 = blockIdx.x * 64;

  f32x4 acc[4][3];
#pragma unroll
  for (int mf = 0; mf < 4; ++mf)
#pragma unroll
    for (int nf = 0; nf < 3; ++nf) acc[mf][nf] = (f32x4)0.0f;

  const char* gb0;
  const char* gb1;
  const char* gb2;
  const char* gb3;
  {
    const int rr = l >> 4;
    const int cb = (l & 15) * 16;
    gb0 = (const char*)(x + (size_t)(m0 + 16 * w + 0 + rr) * 1024) + (cb ^ (((0 + rr) & 7) << 4));
    gb1 = (const char*)(x + (size_t)(m0 + 16 * w + 4 + rr) * 1024) + (cb ^ (((4 + rr) & 7) << 4));
    gb2 = (const char*)(x + (size_t)(m0 + 16 * w + 8 + rr) * 1024) + (cb ^ (((0 + rr) & 7) << 4));
    gb3 = (const char*)(x + (size_t)(m0 + 16 * w + 12 + rr) * 1024) + (cb ^ (((4 + rr) & 7) << 4));
  }

  bf16x8 wf[3][2];
  auto loadw = [&](int kt) {
#pragma unroll
    for (int nf = 0; nf < 3; ++nf) {
      const int colg = w * 48 + nf * 16 + lr;
      const bf16* p = Wt + (colg >> 6) * 65536 + (colg & 63) * 1024 + kt + lg * 8;
      wf[nf][0] = *(const bf16x8*)p;
      wf[nf][1] = *(const bf16x8*)(p + 32);
    }
  };
  auto dma = [&](int t) {
    char* lb = (char*)&xs3[t % 3][16 * w][0];
    const int ko = t * 256;
    GLD16(gb0 + ko, lb + 0 * 1024);
    GLD16(gb1 + ko, lb + 1 * 1024);
    GLD16(gb2 + ko, lb + 2 * 1024);
    GLD16(gb3 + ko, lb + 3 * 1024);
  };

  dma(0);
  dma(1);
  const int sw = (lr & 7) << 4;
#pragma unroll
  for (int t = 0; t < 16; ++t) {
    if (t < 15) {
      asm volatile("s_waitcnt vmcnt(4)" ::: "memory");
    } else {
      asm volatile("s_waitcnt vmcnt(0)" ::: "memory");
    }
    __builtin_amdgcn_sched_barrier(0);
    __builtin_amdgcn_s_barrier();
    __builtin_amdgcn_sched_barrier(0);
    loadw(t * 64);
    if (t < 14) dma(t + 2);
    const char* xb = (const char*)&xs3[t % 3][0][0];
#pragma unroll
    for (int mf = 0; mf < 4; ++mf) {
      const char* rp = xb + (mf * 16 + lr) * 256;
      const f32x4 f0 = *(const f32x4*)(rp + ((lg * 32 + 0) ^ sw));
      const f32x4 f1 = *(const f32x4*)(rp + ((lg * 32 + 16) ^ sw));
      const f32x4 f2 = *(const f32x4*)(rp + (128 + ((lg * 32 + 0) ^ sw)));
      const f32x4 f3 = *(const f32x4*)(rp + (128 + ((lg * 32 + 16) ^ sw)));
      bf16x8 a0, a1;
#pragma unroll
      for (int j = 0; j < 4; ++j) {
        a0[j] = (bf16)f0[j]; a0[4 + j] = (bf16)f1[j];
        a1[j] = (bf16)f2[j]; a1[4 + j] = (bf16)f3[j];
      }
#pragma unroll
      for (int nf = 0; nf < 3; ++nf) {
        acc[mf][nf] = MFMA16(a0, wf[nf][0], acc[mf][nf]);
        acc[mf][nf] = MFMA16(a1, wf[nf][1], acc[mf][nf]);
      }
    }
  }

#pragma unroll
  for (int mf = 0; mf < 4; ++mf) {
#pragma unroll
    for (int nf = 0; nf < 3; ++nf) {
      const int colg = w * 48 + nf * 16 + lr;
      const int mat = colg >> 6, h = colg & 63;
      const int mb = m0 + mf * 16 + lg * 4;
      if (mat == 2) {
        const int b = mb / 320, t = mb % 320;
        bf16x4 o;
#pragma unroll
        for (int r = 0; r < 4; ++r) o[r] = (bf16)acc[mf][nf][r];
        *(bf16x4*)(Vt + ((size_t)b * 64 + h) * 320 + t) = o;
      } else {
        bf16* __restrict__ dst = (mat == 0) ? Kw : Qw;
#pragma unroll
        for (int r = 0; r < 4; ++r) dst[(size_t)(mb + r) * 64 + h] = (bf16)acc[mf][nf][r];
      }
    }
  }
}

// ---------------- Kernel 2: causal attention, front-loaded global traffic ----------------
// S^T = mfma(A=K, B=Q): lane holds q-row t=lane&15, s = st*64 + nf*16 + (lane>>4)*4 + r.
// ALL K tiles global-loaded to regs at block start (one latency for all);
// V tile st issued during phase-1 iter st (lands under phase1+softmax cover).
// Loop bodies contain only LDS ops + MFMA + raw barriers -> no vmcnt stalls
// inside the 4-wave lockstep. Layouts/swizzles identical to round 6 (verified).
template <int QT>
__device__ __forceinline__ void attn_impl(
    int b, const bf16* __restrict__ Qw, const bf16* __restrict__ Kw,
    const bf16* __restrict__ Vt, float* __restrict__ out,
    char* Ks, char* Vs, char* Ps) {
  constexpr int NT = QT + 1;  // 64-wide s-tiles
  const int tid = threadIdx.x;
  const int w = tid >> 6, l = tid & 63;
  const int lr = l & 15, lg = l >> 4;
  const int t0 = QT * 64 + w * 16;
  const int tq = t0 + lr;

  // Q as B-fragments (col = q row tq)
  const bf16* qp = Qw + ((size_t)b * 320 + tq) * 64 + lg * 8;
  const bf16x8 bq0 = *(const bf16x8*)qp;
  const bf16x8 bq1 = *(const bf16x8*)(qp + 32);

  // ---- front-load ALL K tiles into registers (loads overlap each other) ----
  const int krow = w * 16 + (l >> 2);  // staging row 0..63
  const int kcb = (l & 3) * 16;        // 16B chunk in first 64B half
  const int ksw = (krow & 7) << 4;
  const bf16* kbase = Kw + ((size_t)b * 320 + krow) * 64 + (l & 3) * 8;
  bf16x8 kr0[NT], kr1[NT];
#pragma unroll
  for (int st = 0; st < NT; ++st) {
    kr0[st] = *(const bf16x8*)(kbase + st * 4096);
    kr1[st] = *(const bf16x8*)(kbase + st * 4096 + 32);
  }

  const int vrow = w * 16 + (l >> 4);  // base h-row (step 4)
  const bf16* vbase = Vt + ((size_t)b * 64 + vrow) * 320 + (l & 15) * 4;
  uint2 vr[NT][4];

  // ---- phase 1: S^T with LDS-staged K (dbuf); V loads issued per-iter ----
  f32x4 acc[NT * 4];
#pragma unroll
  for (int i = 0; i < NT * 4; ++i) acc[i] = (f32x4)0.0f;

  {  // stage K tile 0
    char* base = Ks + 0 * 8192 + krow * 128;
    *(bf16x8*)(base + (kcb ^ ksw)) = kr0[0];
    *(bf16x8*)(base + ((kcb + 64) ^ ksw)) = kr1[0];
  }
  LGKM0_BARRIER();

  const int asw = (lr & 7) << 4;
#pragma unroll
  for (int st = 0; st < NT; ++st) {
    if (st + 1 < NT) {  // stage next K tile (regs already in flight/landed)
      char* base = Ks + ((st + 1) & 1) * 8192 + krow * 128;
      *(bf16x8*)(base + (kcb ^ ksw)) = kr0[st + 1];
      *(bf16x8*)(base + ((kcb + 64) ^ ksw)) = kr1[st + 1];
    }
    // issue V tile st loads now; they land under remaining phase1 + softmax
#pragma unroll
    for (int i = 0; i < 4; ++i)
      vr[st][i] = *(const uint2*)(vbase + i * 1280 + st * 64);

    const char* kb = Ks + (st & 1) * 8192;
#pragma unroll
    for (int nf = 0; nf < 4; ++nf) {
      const char* rp = kb + (nf * 16 + lr) * 128;
      const bf16x8 a0 = *(const bf16x8*)(rp + ((lg * 16) ^ asw));
      const bf16x8 a1 = *(const bf16x8*)(rp + ((64 + lg * 16) ^ asw));
      acc[st * 4 + nf] = MFMA16(a0, bq0, acc[st * 4 + nf]);
      acc[st * 4 + nf] = MFMA16(a1, bq1, acc[st * 4 + nf]);
    }
    if (st + 1 < NT) LGKM0_BARRIER();
  }

  // stage V tile 0 (overlaps softmax; Vs region untouched so far)
  {
#pragma unroll
    for (int i = 0; i < 4; ++i) {
      const int hl = vrow + i * 4;
      *(uint2*)(Vs + 0 * 8192 + hl * 128 + (((l & 15) * 8) ^ ((hl & 7) << 4))) = vr[0][i];
    }
  }

  // ---- softmax: scale 1/32, causal mask, full row in registers ----
  float mx = -1e30f;
#pragma unroll
  for (int st = 0; st < NT; ++st)
#pragma unroll
    for (int nf = 0; nf < 4; ++nf)
#pragma unroll
      for (int r = 0; r < 4; ++r) {
        const int sg = st * 64 + nf * 16 + lg * 4 + r;
        float v = acc[st * 4 + nf][r] * 0.03125f;
        v = (sg > tq) ? -1e30f : v;
        acc[st * 4 + nf][r] = v;
        mx = fmaxf(mx, v);
      }
  mx = fmaxf(mx, __shfl_xor(mx, 16));
  mx = fmaxf(mx, __shfl_xor(mx, 32));
  float sum = 0.f;
#pragma unroll
  for (int i = 0; i < NT * 4; ++i)
#pragma unroll
    for (int r = 0; r < 4; ++r) {
      const float p = __expf(acc[i][r] - mx);
      acc[i][r] = p;
      sum += p;
    }
  sum += __shfl_xor(sum, 16);
  sum += __shfl_xor(sum, 32);
  const float rinv = 1.0f / sum;

  // ---- phase 2: O = P V (V dbuf in LDS, wave-private P, no vmcnt stalls) ----
  LGKM0_BARRIER();  // V tile 0 visible

  char* Pw = Ps + w * 2048;  // [16 t][128 B] swizzled, wave-private
  f32x4 ao[4];
#pragma unroll
  for (int hf = 0; hf < 4; ++hf) ao[hf] = (f32x4)0.0f;

#pragma unroll
  for (int st = 0; st < NT; ++st) {
    if (st + 1 < NT) {  // stage next V tile (regs long landed)
#pragma unroll
      for (int i = 0; i < 4; ++i) {
        const int hl = vrow + i * 4;
        *(uint2*)(Vs + ((st + 1) & 1) * 8192 + hl * 128 +
                  (((l & 15) * 8) ^ ((hl & 7) << 4))) = vr[st + 1][i];
      }
    }
    // normalized P-tile -> wave-private LDS (b64, swizzled)
#pragma unroll
    for (int nf = 0; nf < 4; ++nf) {
      bf16x4 o;
#pragma unroll
      for (int r = 0; r < 4; ++r) o[r] = (bf16)(acc[st * 4 + nf][r] * rinv);
      *(bf16x4*)(Pw + lr * 128 + ((nf * 32 + lg * 8) ^ asw)) = o;
    }
    const char* vb = Vs + (st & 1) * 8192;
#pragma unroll
    for (int ks = 0; ks < 2; ++ks) {
      const bf16x8 ap = *(const bf16x8*)(Pw + lr * 128 + ((ks * 64 + lg * 16) ^ asw));
#pragma unroll
      for (int hf = 0; hf < 4; ++hf) {
        const bf16x8 bv =
            *(const bf16x8*)(vb + (hf * 16 + lr) * 128 + ((ks * 64 + lg * 16) ^ asw));
        ao[hf] = MFMA16(ap, bv, ao[hf]);
      }
    }
    if (st + 1 < NT) LGKM0_BARRIER();
  }

  const int rowb = t0 + lg * 4;
#pragma unroll
  for (int hf = 0; hf < 4; ++hf)
#pragma unroll
    for (int r = 0; r < 4; ++r)
      out[((size_t)b * 320 + rowb + r) * 64 + hf * 16 + lr] = ao[hf][r];
}

__global__ __launch_bounds__(256) void attn_kernel(
    const bf16* __restrict__ Qw, const bf16* __restrict__ Kw,
    const bf16* __restrict__ Vt, float* __restrict__ out) {
  __shared__ __align__(16) char Ks[2 * 8192];
  __shared__ __align__(16) char Vs[2 * 8192];
  __shared__ __align__(16) char Ps[4 * 2048];
  const int b = blockIdx.x;       // id%8 == b%8: all qt of b on one XCD
  const int qt = 4 - blockIdx.y;  // heavy blocks dispatch first
  switch (qt) {
    case 0: attn_impl<0>(b, Qw, Kw, Vt, out, Ks, Vs, Ps); break;
    case 1: attn_impl<1>(b, Qw, Kw, Vt, out, Ks, Vs, Ps); break;
    case 2: attn_impl<2>(b, Qw, Kw, Vt, out, Ks, Vs, Ps); break;
    case 3: attn_impl<3>(b, Qw, Kw, Vt, out, Ks, Vs, Ps); break;
    default: attn_impl<4>(b, Qw, Kw, Vt, out, Ks, Vs, Ps); break;
  }
}

extern "C" void kernel_launch(void* const* d_in, const int* in_sizes, int n_in,
                              void* d_out, int out_size, void* d_ws, size_t ws_size,
                              hipStream_t stream) {
  const float* x  = (const float*)d_in[0];
  const float* Wk = (const float*)d_in[1];
  const float* Wq = (const float*)d_in[2];
  const float* Wv = (const float*)d_in[3];
  float* out = (float*)d_out;

  bf16* Wt = (bf16*)d_ws;
  bf16* Qw = Wt + 3 * 64 * 1024;
  bf16* Kw = Qw + (size_t)81920 * 64;
  bf16* Vt = Kw + (size_t)81920 * 64;

  hipLaunchKernelGGL(wtrans_kernel, dim3(48), dim3(256), 0, stream, Wk, Wq, Wv, Wt);
  hipLaunchKernelGGL(qkv_kernel, dim3(1280), dim3(256), 0, stream, x, Wt, Qw, Kw, Vt);
  hipLaunchKernelGGL(attn_kernel, dim3(256, 5), dim3(256), 0, stream, Qw, Kw, Vt, out);
}